// Round 1
// baseline (949.351 us; speedup 1.0000x reference)
//
#include <hip/hip_runtime.h>
#include <math.h>

// Problem constants: N=16, L=4096, C=256, NC=512, NR=1, WS=1
// ws layout (byte offsets)
constexpr size_t B_WTX   = 0;                      // 256x256 f32 (Wx transposed, [c][o])
constexpr size_t B_WTY   = B_WTX + 65536*4;
constexpr size_t B_MT    = B_WTY + 65536*4;        // meansT [d][j] 256x512
constexpr size_t B_INVR1 = B_MT + 131072*4;        // 16x256, clamp 1e-12
constexpr size_t B_INVR2 = B_INVR1 + 4096*4;       // 16x256, clamp 5e-5
constexpr size_t B_S0    = B_INVR2 + 4096*4;       // 16x4096
constexpr size_t B_S1    = B_S0 + 65536*4;
constexpr size_t B_S2    = B_S1 + 65536*4;
constexpr size_t B_BS    = B_S2 + 65536*4;
constexpr size_t B_MX    = B_BS + 65536*4;         // 16 f32
constexpr size_t B_Z     = B_MX + 64;              // 16 f32
constexpr size_t B_R2    = B_Z + 64;               // 16x256 f64 (8B aligned: all offsets %64==0)
constexpr size_t B_CODES = B_R2 + 4096*8;          // 16x4096 i32
constexpr size_t B_IDX   = B_CODES + 65536*4;      // sorted->orig
constexpr size_t B_US    = B_IDX + 65536*4;        // orig->sorted rank
constexpr size_t B_XE    = 4*1024*1024;            // x_embed 16x4096x256 f32 (64MB)
constexpr size_t B_YE    = B_XE + (size_t)16777216*4;
constexpr size_t WS_NEED = B_YE + (size_t)16777216*4;

__global__ void k_transpose(const float* __restrict__ Wx, const float* __restrict__ Wy,
                            const float* __restrict__ means,
                            float* __restrict__ WtX, float* __restrict__ WtY,
                            float* __restrict__ MT)
{
    int t = blockIdx.x*256 + threadIdx.x;
    if (t < 65536) {
        int c = t >> 8, o = t & 255;
        WtX[t] = Wx[o*256 + c];
        WtY[t] = Wy[o*256 + c];
    }
    if (t < 131072) {
        int d = t >> 9, j = t & 511;
        MT[t] = means[j*256 + d];
    }
}

// Fused GEMM (x @ W^T + b) + LayerNorm + ReLU.  16 rows x 256 cols per 64-thread block.
__global__ __launch_bounds__(64) void k_embed(
    const float* __restrict__ xin, const float* __restrict__ Wt,
    const float* __restrict__ bias, const float* __restrict__ gg,
    const float* __restrict__ be, float* __restrict__ outp,
    double* __restrict__ r2, int do_r2)
{
    __shared__ __align__(16) float tile[16*256];
    const int tid = threadIdx.x;
    const size_t row0 = (size_t)blockIdx.x * 16;
    const float4* src = (const float4*)(xin + row0*256);
    float4* t4 = (float4*)tile;
    #pragma unroll
    for (int i = 0; i < 16; ++i) t4[i*64 + tid] = src[i*64 + tid];
    __syncthreads();

    float acc[16][4];
    #pragma unroll
    for (int r = 0; r < 16; ++r) { acc[r][0]=0.f; acc[r][1]=0.f; acc[r][2]=0.f; acc[r][3]=0.f; }
    const int j0 = tid*4;
    for (int cc = 0; cc < 256; cc += 4) {
        float4 w0 = *(const float4*)(Wt + (size_t)(cc+0)*256 + j0);
        float4 w1 = *(const float4*)(Wt + (size_t)(cc+1)*256 + j0);
        float4 w2 = *(const float4*)(Wt + (size_t)(cc+2)*256 + j0);
        float4 w3 = *(const float4*)(Wt + (size_t)(cc+3)*256 + j0);
        #pragma unroll
        for (int r = 0; r < 16; ++r) {
            float4 x = *(const float4*)(tile + r*256 + cc);   // broadcast ds_read_b128
            acc[r][0] += x.x*w0.x + x.y*w1.x + x.z*w2.x + x.w*w3.x;
            acc[r][1] += x.x*w0.y + x.y*w1.y + x.z*w2.y + x.w*w3.y;
            acc[r][2] += x.x*w0.z + x.y*w1.z + x.z*w2.z + x.w*w3.z;
            acc[r][3] += x.x*w0.w + x.y*w1.w + x.z*w2.w + x.w*w3.w;
        }
    }
    float4 bb = *(const float4*)(bias + j0);
    float4 g4 = *(const float4*)(gg + j0);
    float4 b4 = *(const float4*)(be + j0);
    double sq0=0.0, sq1=0.0, sq2=0.0, sq3=0.0;
    #pragma unroll
    for (int r = 0; r < 16; ++r) {
        float v0=acc[r][0]+bb.x, v1=acc[r][1]+bb.y, v2=acc[r][2]+bb.z, v3=acc[r][3]+bb.w;
        float s = v0+v1+v2+v3;
        #pragma unroll
        for (int off = 32; off > 0; off >>= 1) s += __shfl_xor(s, off, 64);
        float mu = s * (1.0f/256.0f);
        float d0=v0-mu, d1=v1-mu, d2=v2-mu, d3=v3-mu;
        float ss = d0*d0 + d1*d1 + d2*d2 + d3*d3;
        #pragma unroll
        for (int off = 32; off > 0; off >>= 1) ss += __shfl_xor(ss, off, 64);
        float istd = 1.0f / sqrtf(ss*(1.0f/256.0f) + 1e-5f);
        float o0 = fmaxf(d0*istd*g4.x + b4.x, 0.f);
        float o1 = fmaxf(d1*istd*g4.y + b4.y, 0.f);
        float o2 = fmaxf(d2*istd*g4.z + b4.z, 0.f);
        float o3 = fmaxf(d3*istd*g4.w + b4.w, 0.f);
        float4 o; o.x=o0; o.y=o1; o.z=o2; o.w=o3;
        *(float4*)(outp + (row0 + r)*256 + j0) = o;
        if (do_r2) { sq0 += (double)o0*o0; sq1 += (double)o1*o1;
                     sq2 += (double)o2*o2; sq3 += (double)o3*o3; }
    }
    if (do_r2) {
        int n = (int)(row0 >> 12);
        atomicAdd(&r2[n*256 + j0 + 0], sq0);
        atomicAdd(&r2[n*256 + j0 + 1], sq1);
        atomicAdd(&r2[n*256 + j0 + 2], sq2);
        atomicAdd(&r2[n*256 + j0 + 3], sq3);
    }
}

__global__ void k_finish(const double* __restrict__ r2,
                         float* __restrict__ invr1, float* __restrict__ invr2)
{
    int t = blockIdx.x*256 + threadIdx.x;   // 4096
    float r = (float)sqrt(r2[t]);
    invr1[t] = 1.0f / fmaxf(r, 1e-12f);
    invr2[t] = 1.0f / fmaxf(r, 5e-5f);
}

// dists = xn @ meansT, fused argmax (first-max wins).  16 rows x 512 cols per 128-thread block.
__global__ __launch_bounds__(128) void k_dists(
    const float* __restrict__ X, const float* __restrict__ MT,
    const float* __restrict__ invr, int* __restrict__ codes)
{
    __shared__ __align__(16) float buf[16*512];
    const int tid = threadIdx.x;
    const size_t row0 = (size_t)blockIdx.x * 16;
    const int n = (int)(row0 >> 12);
    {
        const float4* xs = (const float4*)(X + row0*256);
        const float4* ir4 = (const float4*)(invr + n*256);
        float4* b4 = (float4*)buf;
        #pragma unroll
        for (int i = 0; i < 8; ++i) {
            int e = i*128 + tid;          // float4 index within 16x256
            float4 x = xs[e];
            float4 ir = ir4[e & 63];
            x.x *= ir.x; x.y *= ir.y; x.z *= ir.z; x.w *= ir.w;
            b4[e] = x;
        }
    }
    __syncthreads();
    float acc[16][4];
    #pragma unroll
    for (int r = 0; r < 16; ++r) { acc[r][0]=0.f; acc[r][1]=0.f; acc[r][2]=0.f; acc[r][3]=0.f; }
    const int j0 = tid*4;
    for (int cc = 0; cc < 256; cc += 4) {
        float4 m0 = *(const float4*)(MT + (size_t)(cc+0)*512 + j0);
        float4 m1 = *(const float4*)(MT + (size_t)(cc+1)*512 + j0);
        float4 m2 = *(const float4*)(MT + (size_t)(cc+2)*512 + j0);
        float4 m3 = *(const float4*)(MT + (size_t)(cc+3)*512 + j0);
        #pragma unroll
        for (int r = 0; r < 16; ++r) {
            float4 x = *(const float4*)(buf + r*256 + cc);    // broadcast
            acc[r][0] += x.x*m0.x + x.y*m1.x + x.z*m2.x + x.w*m3.x;
            acc[r][1] += x.x*m0.y + x.y*m1.y + x.z*m2.y + x.w*m3.y;
            acc[r][2] += x.x*m0.z + x.y*m1.z + x.z*m2.z + x.w*m3.z;
            acc[r][3] += x.x*m0.w + x.y*m1.w + x.z*m2.w + x.w*m3.w;
        }
    }
    __syncthreads();
    #pragma unroll
    for (int r = 0; r < 16; ++r) {
        float4 v; v.x=acc[r][0]; v.y=acc[r][1]; v.z=acc[r][2]; v.w=acc[r][3];
        *(float4*)(buf + r*512 + j0) = v;
    }
    __syncthreads();
    const int wv = tid >> 6, lane = tid & 63;
    for (int rr = 0; rr < 8; ++rr) {
        int r = wv*8 + rr;
        float bv = -3.0e38f; int bi = 0x7fffffff;
        #pragma unroll
        for (int q = 0; q < 8; ++q) {
            int j = q*64 + lane;
            float v = buf[r*512 + j];
            if (v > bv || (v == bv && j < bi)) { bv = v; bi = j; }
        }
        #pragma unroll
        for (int off = 32; off > 0; off >>= 1) {
            float ov = __shfl_xor(bv, off, 64);
            int   oi = __shfl_xor(bi, off, 64);
            if (ov > bv || (ov == bv && oi < bi)) { bv = ov; bi = oi; }
        }
        if (lane == 0) codes[row0 + r] = bi;
    }
}

// Per-batch stable counting sort of codes in [0,512).
__global__ __launch_bounds__(256) void k_sort(const int* __restrict__ codes,
                                              int* __restrict__ sidx, int* __restrict__ us)
{
    __shared__ int hist[512];
    __shared__ int part[16];
    __shared__ int chunk[256];
    const int n = blockIdx.x, tid = threadIdx.x;
    hist[tid] = 0; hist[tid + 256] = 0;
    __syncthreads();
    const int* cds = codes + n*4096;
    for (int i = 0; i < 16; ++i) atomicAdd(&hist[cds[i*256 + tid]], 1);
    __syncthreads();
    if (tid < 16) { int s = 0; for (int b = 0; b < 32; ++b) s += hist[tid*32 + b]; part[tid] = s; }
    __syncthreads();
    if (tid == 0) { int run = 0; for (int t = 0; t < 16; ++t) { int tmp = part[t]; part[t] = run; run += tmp; } }
    __syncthreads();
    if (tid < 16) { int base = part[tid];
        for (int b = 0; b < 32; ++b) { int tmp = hist[tid*32 + b]; hist[tid*32 + b] = base; base += tmp; } }
    __syncthreads();
    for (int i = 0; i < 16; ++i) {
        int l = i*256 + tid;
        int c = cds[l];
        chunk[tid] = c;
        __syncthreads();
        int rank = hist[c];
        for (int u = 0; u < 256; ++u) {
            if (u < tid && chunk[u] == c) ++rank;
        }
        sidx[n*4096 + rank] = l;
        us[n*4096 + l] = rank;
        __syncthreads();
        atomicAdd(&hist[c], 1);
        __syncthreads();
    }
}

// One wave per sorted position k: the 3 neighbor scores + logsumexp.
__global__ __launch_bounds__(256) void k_bs(
    const float* __restrict__ X, const float* __restrict__ invr,
    const int* __restrict__ sidx,
    float* __restrict__ S0, float* __restrict__ S1,
    float* __restrict__ S2, float* __restrict__ BS)
{
    const int gw = blockIdx.x*4 + (threadIdx.x >> 6);
    const int lane = threadIdx.x & 63;
    const int n = gw >> 12, k = gw & 4095;
    const int base = n*4096;
    const int i0 = sidx[base + k];
    const int im = sidx[base + ((k + 4095) & 4095)];
    const int ip = sidx[base + ((k + 1) & 4095)];
    const float4* x0 = (const float4*)(X + ((size_t)base + i0)*256);
    const float4* xm = (const float4*)(X + ((size_t)base + im)*256);
    const float4* xp = (const float4*)(X + ((size_t)base + ip)*256);
    const float4* ir4 = (const float4*)(invr + n*256);
    float4 a = x0[lane], m_ = xm[lane], p_ = xp[lane], ir = ir4[lane];
    float ax = a.x*ir.x, ay = a.y*ir.y, az = a.z*ir.z, aw = a.w*ir.w;
    float p0 = ax*a.x + ay*a.y + az*a.z + aw*a.w;
    float p1 = ax*m_.x + ay*m_.y + az*m_.z + aw*m_.w;
    float p2 = ax*p_.x + ay*p_.y + az*p_.z + aw*p_.w;
    #pragma unroll
    for (int off = 32; off > 0; off >>= 1) {
        p0 += __shfl_xor(p0, off, 64);
        p1 += __shfl_xor(p1, off, 64);
        p2 += __shfl_xor(p2, off, 64);
    }
    if (lane == 0) {
        float m = fmaxf(p0, fmaxf(p1, p2));
        float bs = m + logf(expf(p0 - m) + expf(p1 - m) + expf(p2 - m));
        S0[gw] = p0; S1[gw] = p1; S2[gw] = p2; BS[gw] = bs;
    }
}

// Per-batch max & sum(exp) of bucket scores.
__global__ __launch_bounds__(256) void k_red(const float* __restrict__ BS,
                                             float* __restrict__ MX, float* __restrict__ Zs)
{
    __shared__ float red[256];
    const int n = blockIdx.x, tid = threadIdx.x;
    const float* b = BS + n*4096;
    float mx = -3.0e38f;
    for (int i = 0; i < 16; ++i) mx = fmaxf(mx, b[i*256 + tid]);
    red[tid] = mx; __syncthreads();
    for (int s = 128; s > 0; s >>= 1) { if (tid < s) red[tid] = fmaxf(red[tid], red[tid + s]); __syncthreads(); }
    float gmx = red[0];
    __syncthreads();
    float sum = 0.f;
    for (int i = 0; i < 16; ++i) sum += expf(b[i*256 + tid] - gmx);
    red[tid] = sum; __syncthreads();
    for (int s = 128; s > 0; s >>= 1) { if (tid < s) red[tid] += red[tid + s]; __syncthreads(); }
    if (tid == 0) { MX[n] = gmx; Zs[n] = red[0]; }
}

// One wave per original position p: gather ys rows, softmax-3 combine, global prob, blend.
__global__ __launch_bounds__(256) void k_final(
    const float* __restrict__ inp, const float* __restrict__ Y,
    const int* __restrict__ sidx, const int* __restrict__ us,
    const float* __restrict__ S0, const float* __restrict__ S1,
    const float* __restrict__ S2, const float* __restrict__ BS,
    const float* __restrict__ MX, const float* __restrict__ Zs,
    const float* __restrict__ alpha_p, float* __restrict__ outp)
{
    const int gw = blockIdx.x*4 + (threadIdx.x >> 6);
    const int lane = threadIdx.x & 63;
    const int n = gw >> 12, p = gw & 4095;
    const int base = n*4096;
    const int k = us[base + p];
    const int i0 = sidx[base + k];
    const int im = sidx[base + ((k + 4095) & 4095)];
    const int ip = sidx[base + ((k + 1) & 4095)];
    const int kk = base + k;
    float bs = BS[kk];
    float w0 = expf(S0[kk] - bs), w1 = expf(S1[kk] - bs), w2 = expf(S2[kk] - bs);
    float alpha = alpha_p[0];
    float coef = (1.0f - alpha) * expf(bs - MX[n]) / Zs[n];
    const float4* y0 = (const float4*)(Y + ((size_t)base + i0)*256);
    const float4* ym = (const float4*)(Y + ((size_t)base + im)*256);
    const float4* yp = (const float4*)(Y + ((size_t)base + ip)*256);
    const float4* iv = (const float4*)(inp + ((size_t)base + p)*256);
    float4 A = y0[lane], Bv = ym[lane], Cv = yp[lane], I = iv[lane];
    float4 o;
    o.x = alpha*I.x + coef*(w0*A.x + w1*Bv.x + w2*Cv.x);
    o.y = alpha*I.y + coef*(w0*A.y + w1*Bv.y + w2*Cv.y);
    o.z = alpha*I.z + coef*(w0*A.z + w1*Bv.z + w2*Cv.z);
    o.w = alpha*I.w + coef*(w0*A.w + w1*Bv.w + w2*Cv.w);
    ((float4*)(outp + ((size_t)base + p)*256))[lane] = o;
}

extern "C" void kernel_launch(void* const* d_in, const int* in_sizes, int n_in,
                              void* d_out, int out_size, void* d_ws, size_t ws_size,
                              hipStream_t stream)
{
    const float* inputs = (const float*)d_in[0];
    const float* Wx  = (const float*)d_in[1];
    const float* bx  = (const float*)d_in[2];
    const float* gx  = (const float*)d_in[3];
    const float* bex = (const float*)d_in[4];
    const float* Wy  = (const float*)d_in[5];
    const float* by  = (const float*)d_in[6];
    const float* gy  = (const float*)d_in[7];
    const float* bey = (const float*)d_in[8];
    const float* means = (const float*)d_in[9];
    const float* alpha = (const float*)d_in[10];

    if (ws_size < WS_NEED) return;  // loud failure (output stays poisoned)

    char* ws = (char*)d_ws;
    float*  WtX   = (float*)(ws + B_WTX);
    float*  WtY   = (float*)(ws + B_WTY);
    float*  MT    = (float*)(ws + B_MT);
    float*  invr1 = (float*)(ws + B_INVR1);
    float*  invr2 = (float*)(ws + B_INVR2);
    float*  S0    = (float*)(ws + B_S0);
    float*  S1    = (float*)(ws + B_S1);
    float*  S2    = (float*)(ws + B_S2);
    float*  BSb   = (float*)(ws + B_BS);
    float*  MX    = (float*)(ws + B_MX);
    float*  Zs    = (float*)(ws + B_Z);
    double* r2    = (double*)(ws + B_R2);
    int*    codes = (int*)(ws + B_CODES);
    int*    sidx  = (int*)(ws + B_IDX);
    int*    us    = (int*)(ws + B_US);
    float*  XE    = (float*)(ws + B_XE);
    float*  YE    = (float*)(ws + B_YE);
    float*  outp  = (float*)d_out;

    hipMemsetAsync(r2, 0, 4096*8, stream);
    k_transpose<<<512, 256, 0, stream>>>(Wx, Wy, means, WtX, WtY, MT);
    k_embed<<<4096, 64, 0, stream>>>(inputs, WtX, bx, gx, bex, XE, r2, 1);
    k_embed<<<4096, 64, 0, stream>>>(inputs, WtY, by, gy, bey, YE, r2, 0);
    k_finish<<<16, 256, 0, stream>>>(r2, invr1, invr2);
    k_dists<<<4096, 128, 0, stream>>>(XE, MT, invr1, codes);
    k_sort<<<16, 256, 0, stream>>>(codes, sidx, us);
    k_bs<<<16384, 256, 0, stream>>>(XE, invr2, sidx, S0, S1, S2, BSb);
    k_red<<<16, 256, 0, stream>>>(BSb, MX, Zs);
    k_final<<<16384, 256, 0, stream>>>(inputs, YE, sidx, us, S0, S1, S2, BSb, MX, Zs, alpha, outp);
}

// Round 7
// 794.644 us; speedup vs baseline: 1.1947x; 1.1947x over previous
//
#include <hip/hip_runtime.h>
#include <math.h>

// Problem constants: N=16, L=4096, C=256, NC=512, NR=1, WS=1
typedef _Float16 half8 __attribute__((ext_vector_type(8)));
typedef float    f32x4 __attribute__((ext_vector_type(4)));

// ws layout (byte offsets)
constexpr size_t B_WXH   = 0;                       // 256x256 f16 hi of Wx, natural [o][c]
constexpr size_t B_WXL   = 131072;
constexpr size_t B_WYH   = 262144;
constexpr size_t B_WYL   = 393216;
constexpr size_t B_MH    = 524288;                  // 512x256 f16 hi of means, natural [j][d]
constexpr size_t B_ML    = 786432;
constexpr size_t B_INVR1 = 1048576;                 // 16x256 f32, clamp 1e-12
constexpr size_t B_INVR2 = 1064960;                 // 16x256 f32, clamp 5e-5
constexpr size_t B_S0    = 1081344;                 // 16x4096 f32
constexpr size_t B_S1    = 1343488;
constexpr size_t B_S2    = 1605632;
constexpr size_t B_BS    = 1867776;
constexpr size_t B_MX    = 2129920;                 // 16 f32
constexpr size_t B_Z     = 2129984;                 // 16 f32
constexpr size_t B_R2    = 2130048;                 // 16x256 f64
constexpr size_t B_CODES = 2162816;                 // 16x4096 i32
constexpr size_t B_IDX   = 2424960;                 // sorted->orig
constexpr size_t B_US    = 2687104;                 // orig->sorted rank
constexpr size_t B_XE    = 4194304;                 // x_embed 16x4096x256 f32 (64MB)
constexpr size_t B_YE    = 71303168;
constexpr size_t WS_NEED = 138412032;

// Split Wx/Wy/means into f16 hi/lo pairs (natural layout; MFMA B-frags read rows directly).
__global__ void k_prep(const float* __restrict__ Wx, const float* __restrict__ Wy,
                       const float* __restrict__ means,
                       _Float16* __restrict__ WXH, _Float16* __restrict__ WXL,
                       _Float16* __restrict__ WYH, _Float16* __restrict__ WYL,
                       _Float16* __restrict__ MH,  _Float16* __restrict__ ML)
{
    int t = blockIdx.x*256 + threadIdx.x;
    if (t < 65536) {
        float a = Wx[t]; _Float16 ha = (_Float16)a;
        WXH[t] = ha; WXL[t] = (_Float16)(a - (float)ha);
        float b = Wy[t]; _Float16 hb = (_Float16)b;
        WYH[t] = hb; WYL[t] = (_Float16)(b - (float)hb);
    }
    if (t < 131072) {
        float m = means[t]; _Float16 hm = (_Float16)m;
        MH[t] = hm; ML[t] = (_Float16)(m - (float)hm);
    }
}

// Fused GEMM (x @ W^T + b) + LayerNorm + ReLU via split-f16 3-pass MFMA.
// One wave per 16 rows x 256 cols. A-frags converted f32->f16 hi/lo in regs (no LDS).
// mfma_f32_16x16x32_f16: A lane: row=l&15, k=8*(l>>4)+e ; B lane: col=l&15, k=8*(l>>4)+e
// D lane: col=l&15, row=4*(l>>4)+v   (m89/m91-verified C/D mapping)
__global__ __launch_bounds__(64) void k_embed_mfma(
    const float* __restrict__ xin,
    const _Float16* __restrict__ WH, const _Float16* __restrict__ WL,
    const float* __restrict__ bias, const float* __restrict__ gg,
    const float* __restrict__ be, float* __restrict__ outp,
    double* __restrict__ r2, int do_r2)
{
    const int l = threadIdx.x;
    const int row16 = l & 15, kgrp = l >> 4;
    const size_t row0 = (size_t)blockIdx.x * 16;
    f32x4 acc[16];
    #pragma unroll
    for (int t = 0; t < 16; ++t) acc[t] = (f32x4){0.f, 0.f, 0.f, 0.f};

    for (int ks = 0; ks < 8; ++ks) {
        const int kb = ks*32 + kgrp*8;
        const float* xp = xin + (row0 + row16)*256 + kb;
        float4 xa = *(const float4*)xp;
        float4 xb = *(const float4*)(xp + 4);
        float xv[8] = {xa.x, xa.y, xa.z, xa.w, xb.x, xb.y, xb.z, xb.w};
        half8 ah, al;
        #pragma unroll
        for (int e = 0; e < 8; ++e) {
            _Float16 h = (_Float16)xv[e];
            ah[e] = h;
            al[e] = (_Float16)(xv[e] - (float)h);
        }
        #pragma unroll
        for (int t = 0; t < 16; ++t) {
            const size_t wo = (size_t)(t*16 + row16)*256 + kb;
            half8 bh = *(const half8*)(WH + wo);
            half8 bl = *(const half8*)(WL + wo);
            acc[t] = __builtin_amdgcn_mfma_f32_16x16x32_f16(ah, bh, acc[t], 0, 0, 0);
            acc[t] = __builtin_amdgcn_mfma_f32_16x16x32_f16(ah, bl, acc[t], 0, 0, 0);
            acc[t] = __builtin_amdgcn_mfma_f32_16x16x32_f16(al, bh, acc[t], 0, 0, 0);
        }
    }
    // epilogue: rows r = 4*kgrp+v, cols c = 16t+row16. Bias + LN over c + ReLU.
    float bias_t[16], g_t[16], be_t[16];
    #pragma unroll
    for (int t = 0; t < 16; ++t) {
        int c = t*16 + row16;
        bias_t[t] = bias[c]; g_t[t] = gg[c]; be_t[t] = be[c];
    }
    #pragma unroll
    for (int t = 0; t < 16; ++t) {
        float b = bias_t[t];
        acc[t][0] += b; acc[t][1] += b; acc[t][2] += b; acc[t][3] += b;
    }
    float sum[4] = {0.f, 0.f, 0.f, 0.f};
    #pragma unroll
    for (int t = 0; t < 16; ++t) {
        sum[0] += acc[t][0]; sum[1] += acc[t][1];
        sum[2] += acc[t][2]; sum[3] += acc[t][3];
    }
    #pragma unroll
    for (int v = 0; v < 4; ++v) {
        #pragma unroll
        for (int off = 1; off < 16; off <<= 1) sum[v] += __shfl_xor(sum[v], off, 64);
    }
    float mu[4], ssum[4] = {0.f, 0.f, 0.f, 0.f};
    #pragma unroll
    for (int v = 0; v < 4; ++v) mu[v] = sum[v] * (1.0f/256.0f);
    #pragma unroll
    for (int t = 0; t < 16; ++t) {
        #pragma unroll
        for (int v = 0; v < 4; ++v) { float d = acc[t][v] - mu[v]; ssum[v] += d*d; }
    }
    float istd[4];
    #pragma unroll
    for (int v = 0; v < 4; ++v) {
        #pragma unroll
        for (int off = 1; off < 16; off <<= 1) ssum[v] += __shfl_xor(ssum[v], off, 64);
        istd[v] = 1.0f / sqrtf(ssum[v]*(1.0f/256.0f) + 1e-5f);
    }
    const int n = (int)(row0 >> 12);
    #pragma unroll
    for (int t = 0; t < 16; ++t) {
        float sq = 0.f;
        #pragma unroll
        for (int v = 0; v < 4; ++v) {
            float o = fmaxf((acc[t][v] - mu[v])*istd[v]*g_t[t] + be_t[t], 0.f);
            outp[(row0 + kgrp*4 + v)*256 + t*16 + row16] = o;
            sq += o*o;
        }
        if (do_r2) {
            sq += __shfl_xor(sq, 16, 64);
            sq += __shfl_xor(sq, 32, 64);
            if (kgrp == 0) atomicAdd(&r2[n*256 + t*16 + row16], (double)sq);
        }
    }
}

__global__ void k_finish(const double* __restrict__ r2,
                         float* __restrict__ invr1, float* __restrict__ invr2)
{
    int t = blockIdx.x*256 + threadIdx.x;   // 4096
    float r = (float)sqrt(r2[t]);
    invr1[t] = 1.0f / fmaxf(r, 1e-12f);
    invr2[t] = 1.0f / fmaxf(r, 5e-5f);
}

// dists = (x*invr1) @ meansT via split-f16 3-pass MFMA, fused in-register argmax
// (first-max wins). 16 rows per block; 2 waves, each 256 of the 512 cols.
__global__ __launch_bounds__(128) void k_dists_mfma(
    const float* __restrict__ X,
    const _Float16* __restrict__ MH, const _Float16* __restrict__ ML,
    const float* __restrict__ invr, int* __restrict__ codes)
{
    __shared__ float wbv[2][16];
    __shared__ int   wbi[2][16];
    const int tid = threadIdx.x, l = tid & 63, w = tid >> 6;
    const int row16 = l & 15, kgrp = l >> 4;
    const size_t row0 = (size_t)blockIdx.x * 16;
    const int n = (int)(row0 >> 12);
    const int cbase = w * 256;
    f32x4 acc[16];
    #pragma unroll
    for (int t = 0; t < 16; ++t) acc[t] = (f32x4){0.f, 0.f, 0.f, 0.f};

    for (int ks = 0; ks < 8; ++ks) {
        const int kb = ks*32 + kgrp*8;
        const float* xp = X + (row0 + row16)*256 + kb;
        float4 xa = *(const float4*)xp;
        float4 xb = *(const float4*)(xp + 4);
        const float* ip = invr + n*256 + kb;
        float4 ia = *(const float4*)ip;
        float4 ib = *(const float4*)(ip + 4);
        float xv[8] = {xa.x*ia.x, xa.y*ia.y, xa.z*ia.z, xa.w*ia.w,
                       xb.x*ib.x, xb.y*ib.y, xb.z*ib.z, xb.w*ib.w};
        half8 ah, al;
        #pragma unroll
        for (int e = 0; e < 8; ++e) {
            _Float16 h = (_Float16)xv[e];
            ah[e] = h;
            al[e] = (_Float16)(xv[e] - (float)h);
        }
        #pragma unroll
        for (int t = 0; t < 16; ++t) {
            const size_t mo = (size_t)(cbase + t*16 + row16)*256 + kb;
            half8 bh = *(const half8*)(MH + mo);
            half8 bl = *(const half8*)(ML + mo);
            acc[t] = __builtin_amdgcn_mfma_f32_16x16x32_f16(ah, bh, acc[t], 0, 0, 0);
            acc[t] = __builtin_amdgcn_mfma_f32_16x16x32_f16(ah, bl, acc[t], 0, 0, 0);
            acc[t] = __builtin_amdgcn_mfma_f32_16x16x32_f16(al, bh, acc[t], 0, 0, 0);
        }
    }
    // per-row argmax; within a lane cols ascend with t, so strict '>' keeps first
    float bv[4]; int bi[4];
    #pragma unroll
    for (int v = 0; v < 4; ++v) { bv[v] = -3.0e38f; bi[v] = 0x7fffffff; }
    #pragma unroll
    for (int t = 0; t < 16; ++t) {
        int c = cbase + t*16 + row16;
        #pragma unroll
        for (int v = 0; v < 4; ++v) {
            float val = acc[t][v];
            if (val > bv[v]) { bv[v] = val; bi[v] = c; }
        }
    }
    #pragma unroll
    for (int v = 0; v < 4; ++v) {
        #pragma unroll
        for (int off = 1; off < 16; off <<= 1) {
            float ov = __shfl_xor(bv[v], off, 64);
            int   oi = __shfl_xor(bi[v], off, 64);
            if (ov > bv[v] || (ov == bv[v] && oi < bi[v])) { bv[v] = ov; bi[v] = oi; }
        }
        if (row16 == 0) { wbv[w][kgrp*4 + v] = bv[v]; wbi[w][kgrp*4 + v] = bi[v]; }
    }
    __syncthreads();
    if (tid < 16) {
        float b0 = wbv[0][tid], b1 = wbv[1][tid];
        int   i0 = wbi[0][tid], i1 = wbi[1][tid];
        int bi_ = (b1 > b0 || (b1 == b0 && i1 < i0)) ? i1 : i0;
        codes[row0 + tid] = bi_;
    }
}

// Per-batch stable counting sort of codes in [0,512).
__global__ __launch_bounds__(256) void k_sort(const int* __restrict__ codes,
                                              int* __restrict__ sidx, int* __restrict__ us)
{
    __shared__ int hist[512];
    __shared__ int part[16];
    __shared__ int chunk[256];
    const int n = blockIdx.x, tid = threadIdx.x;
    hist[tid] = 0; hist[tid + 256] = 0;
    __syncthreads();
    const int* cds = codes + n*4096;
    for (int i = 0; i < 16; ++i) atomicAdd(&hist[cds[i*256 + tid]], 1);
    __syncthreads();
    if (tid < 16) { int s = 0; for (int b = 0; b < 32; ++b) s += hist[tid*32 + b]; part[tid] = s; }
    __syncthreads();
    if (tid == 0) { int run = 0; for (int t = 0; t < 16; ++t) { int tmp = part[t]; part[t] = run; run += tmp; } }
    __syncthreads();
    if (tid < 16) { int base = part[tid];
        for (int b = 0; b < 32; ++b) { int tmp = hist[tid*32 + b]; hist[tid*32 + b] = base; base += tmp; } }
    __syncthreads();
    for (int i = 0; i < 16; ++i) {
        int lix = i*256 + tid;
        int c = cds[lix];
        chunk[tid] = c;
        __syncthreads();
        int rank = hist[c];
        for (int u = 0; u < 256; ++u) {
            if (u < tid && chunk[u] == c) ++rank;
        }
        sidx[n*4096 + rank] = lix;
        us[n*4096 + lix] = rank;
        __syncthreads();
        atomicAdd(&hist[c], 1);
        __syncthreads();
    }
}

// One wave per sorted position k: the 3 neighbor scores + logsumexp.
__global__ __launch_bounds__(256) void k_bs(
    const float* __restrict__ X, const float* __restrict__ invr,
    const int* __restrict__ sidx,
    float* __restrict__ S0, float* __restrict__ S1,
    float* __restrict__ S2, float* __restrict__ BS)
{
    const int gw = blockIdx.x*4 + (threadIdx.x >> 6);
    const int lane = threadIdx.x & 63;
    const int n = gw >> 12, k = gw & 4095;
    const int base = n*4096;
    const int i0 = sidx[base + k];
    const int im = sidx[base + ((k + 4095) & 4095)];
    const int ip = sidx[base + ((k + 1) & 4095)];
    const float4* x0 = (const float4*)(X + ((size_t)base + i0)*256);
    const float4* xm = (const float4*)(X + ((size_t)base + im)*256);
    const float4* xp = (const float4*)(X + ((size_t)base + ip)*256);
    const float4* ir4 = (const float4*)(invr + n*256);
    float4 a = x0[lane], m_ = xm[lane], p_ = xp[lane], ir = ir4[lane];
    float ax = a.x*ir.x, ay = a.y*ir.y, az = a.z*ir.z, aw = a.w*ir.w;
    float p0 = ax*a.x + ay*a.y + az*a.z + aw*a.w;
    float p1 = ax*m_.x + ay*m_.y + az*m_.z + aw*m_.w;
    float p2 = ax*p_.x + ay*p_.y + az*p_.z + aw*p_.w;
    #pragma unroll
    for (int off = 32; off > 0; off >>= 1) {
        p0 += __shfl_xor(p0, off, 64);
        p1 += __shfl_xor(p1, off, 64);
        p2 += __shfl_xor(p2, off, 64);
    }
    if (lane == 0) {
        float m = fmaxf(p0, fmaxf(p1, p2));
        float bs = m + logf(expf(p0 - m) + expf(p1 - m) + expf(p2 - m));
        S0[gw] = p0; S1[gw] = p1; S2[gw] = p2; BS[gw] = bs;
    }
}

// Per-batch max & sum(exp) of bucket scores.
__global__ __launch_bounds__(256) void k_red(const float* __restrict__ BS,
                                             float* __restrict__ MX, float* __restrict__ Zs)
{
    __shared__ float red[256];
    const int n = blockIdx.x, tid = threadIdx.x;
    const float* b = BS + n*4096;
    float mx = -3.0e38f;
    for (int i = 0; i < 16; ++i) mx = fmaxf(mx, b[i*256 + tid]);
    red[tid] = mx; __syncthreads();
    for (int s = 128; s > 0; s >>= 1) { if (tid < s) red[tid] = fmaxf(red[tid], red[tid + s]); __syncthreads(); }
    float gmx = red[0];
    __syncthreads();
    float sum = 0.f;
    for (int i = 0; i < 16; ++i) sum += expf(b[i*256 + tid] - gmx);
    red[tid] = sum; __syncthreads();
    for (int s = 128; s > 0; s >>= 1) { if (tid < s) red[tid] += red[tid + s]; __syncthreads(); }
    if (tid == 0) { MX[n] = gmx; Zs[n] = red[0]; }
}

// One wave per original position p: gather ys rows, softmax-3 combine, global prob, blend.
__global__ __launch_bounds__(256) void k_final(
    const float* __restrict__ inp, const float* __restrict__ Y,
    const int* __restrict__ sidx, const int* __restrict__ us,
    const float* __restrict__ S0, const float* __restrict__ S1,
    const float* __restrict__ S2, const float* __restrict__ BS,
    const float* __restrict__ MX, const float* __restrict__ Zs,
    const float* __restrict__ alpha_p, float* __restrict__ outp)
{
    const int gw = blockIdx.x*4 + (threadIdx.x >> 6);
    const int lane = threadIdx.x & 63;
    const int n = gw >> 12, p = gw & 4095;
    const int base = n*4096;
    const int k = us[base + p];
    const int i0 = sidx[base + k];
    const int im = sidx[base + ((k + 4095) & 4095)];
    const int ip = sidx[base + ((k + 1) & 4095)];
    const int kk = base + k;
    float bs = BS[kk];
    float w0 = expf(S0[kk] - bs), w1 = expf(S1[kk] - bs), w2 = expf(S2[kk] - bs);
    float alpha = alpha_p[0];
    float coef = (1.0f - alpha) * expf(bs - MX[n]) / Zs[n];
    const float4* y0 = (const float4*)(Y + ((size_t)base + i0)*256);
    const float4* ym = (const float4*)(Y + ((size_t)base + im)*256);
    const float4* yp = (const float4*)(Y + ((size_t)base + ip)*256);
    const float4* iv = (const float4*)(inp + ((size_t)base + p)*256);
    float4 A = y0[lane], Bv = ym[lane], Cv = yp[lane], I = iv[lane];
    float4 o;
    o.x = alpha*I.x + coef*(w0*A.x + w1*Bv.x + w2*Cv.x);
    o.y = alpha*I.y + coef*(w0*A.y + w1*Bv.y + w2*Cv.y);
    o.z = alpha*I.z + coef*(w0*A.z + w1*Bv.z + w2*Cv.z);
    o.w = alpha*I.w + coef*(w0*A.w + w1*Bv.w + w2*Cv.w);
    ((float4*)(outp + ((size_t)base + p)*256))[lane] = o;
}

extern "C" void kernel_launch(void* const* d_in, const int* in_sizes, int n_in,
                              void* d_out, int out_size, void* d_ws, size_t ws_size,
                              hipStream_t stream)
{
    const float* inputs = (const float*)d_in[0];
    const float* Wx  = (const float*)d_in[1];
    const float* bx  = (const float*)d_in[2];
    const float* gx  = (const float*)d_in[3];
    const float* bex = (const float*)d_in[4];
    const float* Wy  = (const float*)d_in[5];
    const float* by  = (const float*)d_in[6];
    const float* gy  = (const float*)d_in[7];
    const float* bey = (const float*)d_in[8];
    const float* means = (const float*)d_in[9];
    const float* alpha = (const float*)d_in[10];

    if (ws_size < WS_NEED) return;  // loud failure (output stays poisoned)

    char* ws = (char*)d_ws;
    _Float16* WXH = (_Float16*)(ws + B_WXH);
    _Float16* WXL = (_Float16*)(ws + B_WXL);
    _Float16* WYH = (_Float16*)(ws + B_WYH);
    _Float16* WYL = (_Float16*)(ws + B_WYL);
    _Float16* MH  = (_Float16*)(ws + B_MH);
    _Float16* ML  = (_Float16*)(ws + B_ML);
    float*  invr1 = (float*)(ws + B_INVR1);
    float*  invr2 = (float*)(ws + B_INVR2);
    float*  S0    = (float*)(ws + B_S0);
    float*  S1    = (float*)(ws + B_S1);
    float*  S2    = (float*)(ws + B_S2);
    float*  BSb   = (float*)(ws + B_BS);
    float*  MX    = (float*)(ws + B_MX);
    float*  Zs    = (float*)(ws + B_Z);
    double* r2    = (double*)(ws + B_R2);
    int*    codes = (int*)(ws + B_CODES);
    int*    sidx  = (int*)(ws + B_IDX);
    int*    us    = (int*)(ws + B_US);
    float*  XE    = (float*)(ws + B_XE);
    float*  YE    = (float*)(ws + B_YE);
    float*  outp  = (float*)d_out;

    hipMemsetAsync(r2, 0, 4096*8, stream);
    k_prep<<<512, 256, 0, stream>>>(Wx, Wy, means, WXH, WXL, WYH, WYL, MH, ML);
    k_embed_mfma<<<4096, 64, 0, stream>>>(inputs, WXH, WXL, bx, gx, bex, XE, r2, 1);
    k_embed_mfma<<<4096, 64, 0, stream>>>(inputs, WYH, WYL, by, gy, bey, YE, r2, 0);
    k_finish<<<16, 256, 0, stream>>>(r2, invr1, invr2);
    k_dists_mfma<<<4096, 128, 0, stream>>>(XE, MH, ML, invr1, codes);
    k_sort<<<16, 256, 0, stream>>>(codes, sidx, us);
    k_bs<<<16384, 256, 0, stream>>>(XE, invr2, sidx, S0, S1, S2, BSb);
    k_red<<<16, 256, 0, stream>>>(BSb, MX, Zs);
    k_final<<<16384, 256, 0, stream>>>(inputs, YE, sidx, us, S0, S1, S2, BSb, MX, Zs, alpha, outp);
}